// Round 17
// baseline (356.263 us; speedup 1.0000x reference)
//
#include <hip/hip_runtime.h>
#include <hip/hip_bf16.h>
#include <math.h>

#define NN   65536      // total nodes
#define NPER 1024       // nodes per graph
#define NE   1048576    // edges
#define NB   64         // graphs
#define EPG  16384      // edges per graph (NE/NB, edges grouped by graph)

typedef __attribute__((ext_vector_type(8))) short short8;   // 8 bf16 = 4 VGPR
typedef __attribute__((ext_vector_type(4))) float f32x4;    // MFMA acc

// ---------------- CSR build: one block per graph (LDS bucket sort) ----------------
// stores LOCAL src ids (0..1023) for direct LDS indexing in gatherL.

__global__ __launch_bounds__(1024) void csr_kernel(const int* __restrict__ ei,
      int* __restrict__ off, int* __restrict__ adj){
  __shared__ int hist[1024];
  __shared__ int wsum[16];
  const int g = ((int)blockIdx.x & 7)*8 + ((int)blockIdx.x >> 3);   // graph g -> XCD g/8
  const int t = threadIdx.x;
  const int ebase = g*EPG, nbase = g*NPER;
  hist[t] = 0;
  __syncthreads();
  int srcs[16], dls[16];
  #pragma unroll
  for (int i = 0; i < 16; ++i){
    int e = ebase + t + i*1024;
    srcs[i] = ei[e] - nbase;           // local src id
    dls[i]  = ei[NE + e] - nbase;
    atomicAdd(&hist[dls[i]], 1);
  }
  __syncthreads();
  int v = hist[t];
  int lane = t & 63, wid = t >> 6;
  int s = v;
  #pragma unroll
  for (int d = 1; d < 64; d <<= 1){
    int src = (lane >= d) ? (lane - d) : lane;
    int u = __shfl(s, src);
    if (lane >= d) s += u;
  }
  if (lane == 63) wsum[wid] = s;
  __syncthreads();
  if (wid == 0){
    int ws = (lane < 16) ? wsum[lane] : 0;
    #pragma unroll
    for (int d = 1; d < 16; d <<= 1){
      int src = (lane >= d) ? (lane - d) : lane;
      int u = __shfl(ws, src);
      if (lane >= d) ws += u;
    }
    if (lane < 16) wsum[lane] = ws;
  }
  __syncthreads();
  int base = (wid > 0) ? wsum[wid - 1] : 0;
  int excl = base + s - v;
  __syncthreads();
  hist[t] = excl;                        // becomes cursor
  off[nbase + t] = ebase + excl;
  if (g == NB - 1 && t == 1023) off[NN] = NE;
  __syncthreads();
  #pragma unroll
  for (int i = 0; i < 16; ++i){
    int pos = atomicAdd(&hist[dls[i]], 1);
    adj[ebase + pos] = srcs[i];
  }
}

// ---------------- LDS-staged aggregation: agg[w] = sum_e scale[src]*y[src] ----------------
// block = (graph g swizzled to XCD g/8, 16-feature slice fq). Stage yq[1024][16] (64KB)
// with scale PRE-APPLIED (dead src -> exact 0), then walk edges reading LDS only.
// wave per dst node (16 waves x 64 nodes), 4 sub-groups x 16 lanes, 8 edges/iter,
// branch-free tail via clamp + 0-select. Dead dst nodes skipped (agg stale, never read).

__global__ __launch_bounds__(1024) void gatherL_kernel(const float* __restrict__ x, int F,
      const int* __restrict__ off, const int* __restrict__ adjL,
      const float* __restrict__ scale, const int* __restrict__ alive,
      float* __restrict__ agg){
  __shared__ float yq[1024*16];
  const int g = ((int)blockIdx.x & 7)*8 + ((int)blockIdx.x >> 3);   // graph g -> XCD g/8
  const int fq = blockIdx.y;                  // slice 0..F/16-1
  const int t = threadIdx.x;
  const int nbase = g*NPER;
  {
    const float sc = scale ? scale[nbase + t] : 1.f;
    const float* xb = x + (size_t)(nbase + t)*F + fq*16;
    float4 v0 = *(const float4*)(xb);
    float4 v1 = *(const float4*)(xb + 4);
    float4 v2 = *(const float4*)(xb + 8);
    float4 v3 = *(const float4*)(xb + 12);
    v0.x *= sc; v0.y *= sc; v0.z *= sc; v0.w *= sc;
    v1.x *= sc; v1.y *= sc; v1.z *= sc; v1.w *= sc;
    v2.x *= sc; v2.y *= sc; v2.z *= sc; v2.w *= sc;
    v3.x *= sc; v3.y *= sc; v3.z *= sc; v3.w *= sc;
    *(float4*)&yq[t*16 + 0]  = v0;
    *(float4*)&yq[t*16 + 4]  = v1;
    *(float4*)&yq[t*16 + 8]  = v2;
    *(float4*)&yq[t*16 + 12] = v3;
  }
  __syncthreads();
  const int wv = t >> 6, lane = t & 63;
  const int sub = lane >> 4, fl = lane & 15;
  for (int n = 0; n < 64; ++n){
    const int w = nbase + wv*64 + n;
    if (alive && !alive[w]) continue;
    const int s0 = off[w], s1 = off[w+1];
    float a = 0.f;
    for (int e = s0; e < s1; e += 8){
      int e0 = e + sub, e1 = e + 4 + sub;
      bool ok0 = e0 < s1, ok1 = e1 < s1;
      int src0 = adjL[ok0 ? e0 : (s1 - 1)];
      int src1 = adjL[ok1 ? e1 : (s1 - 1)];
      float y0 = yq[src0*16 + fl];
      float y1 = yq[src1*16 + fl];
      a += ok0 ? y0 : 0.f;
      a += ok1 ? y1 : 0.f;
    }
    a += __shfl_xor(a, 16);
    a += __shfl_xor(a, 32);
    if (lane < 16) agg[(size_t)w*128 + fq*16 + fl] = a;
  }
}

// ---------------- W prep (all 3 levels, one launch) ----------------

__global__ __launch_bounds__(256) void wsplit_all_kernel(
      const float* __restrict__ Wr0, const float* __restrict__ Wn0,
      const float* __restrict__ Wr1, const float* __restrict__ Wn1,
      const float* __restrict__ Wr2, const float* __restrict__ Wn2,
      unsigned short* __restrict__ WTh, unsigned short* __restrict__ WTl){
  int idx = blockIdx.x*256 + threadIdx.x;       // 0..81919
  int rel, Kcat, Kx, base;
  const float *Wr, *Wn;
  if (idx < 16384){ rel = idx;          Kcat = 128; Kx = 64;  base = 0;     Wr = Wr0; Wn = Wn0; }
  else if (idx < 49152){ rel = idx - 16384; Kcat = 256; Kx = 128; base = 16384; Wr = Wr1; Wn = Wn1; }
  else { rel = idx - 49152; Kcat = 256; Kx = 128; base = 49152; Wr = Wr2; Wn = Wn2; }
  int c = rel & 127, k = rel >> 7;
  float w = (k < Kx) ? Wr[k*128 + c] : Wn[(k - Kx)*128 + c];
  __hip_bfloat16 h = __float2bfloat16(w);
  float hf = __bfloat162float(h);
  __hip_bfloat16 l = __float2bfloat16(w - hf);
  WTh[base + c*Kcat + k] = reinterpret_cast<unsigned short&>(h);
  WTl[base + c*Kcat + k] = reinterpret_cast<unsigned short&>(l);
}

// ---------------- conv via bf16x3 MFMA: y = relu((scale.x)@Wr + agg@Wn + b), score = y.p ----

__global__ __launch_bounds__(256, 2) void conv_kernel(const float* __restrict__ xsrc, int strideX, int ntx,
      const float* aggb, int nta,
      const unsigned short* __restrict__ WTh, const unsigned short* __restrict__ WTl, int Kcat,
      const float* __restrict__ bias, const float* __restrict__ p, const float* __restrict__ scaleX,
      float* yout, float* __restrict__ score){
  __shared__ unsigned short XhL[128*32], XlL[128*32];
  __shared__ unsigned short WhL[128*32], WlL[128*32];
  __shared__ float sbuf[128*2];
  const int tid = threadIdx.x;
  const int rblk = ((int)blockIdx.x & 7) * ((int)gridDim.x >> 3) + ((int)blockIdx.x >> 3);
  const int row0 = rblk * 128;
  const int srow = tid & 127;          // staging row (X) / col (W)
  const int shalf = tid >> 7;          // staging k-half (16 k each)
  const int lane = tid & 63;
  const int wid = tid >> 6;            // 4 waves: 2x2
  const int wr = wid >> 1, wc = wid & 1;
  const int l15 = lane & 15, lkq = lane >> 4;

  const float xscale = scaleX ? scaleX[row0 + srow] : 1.f;

  f32x4 acc[4][4];
  #pragma unroll
  for (int m = 0; m < 4; ++m)
    #pragma unroll
    for (int j = 0; j < 4; ++j)
      acc[m][j] = (f32x4){0.f, 0.f, 0.f, 0.f};

  const int nt = ntx + nta;
  for (int t = 0; t < nt; ++t){
    __syncthreads();                   // previous tile's compute done
    // ---- stage X (fp32 -> scale -> bf16 hi/lo) ----
    {
      const float* Xs   = (t < ntx) ? xsrc : aggb;
      const int stride  = (t < ntx) ? strideX : 128;
      const int kc      = (t < ntx) ? t*32 : (t - ntx)*32;
      const float sc    = (t < ntx) ? xscale : 1.f;
      #pragma unroll
      for (int kq2 = 0; kq2 < 2; ++kq2){
        const int kq = shalf*2 + kq2;
        const float* xp = Xs + (size_t)(row0 + srow)*stride + kc + kq*8;
        float4 v0 = *(const float4*)(xp);
        float4 v1 = *(const float4*)(xp + 4);
        float vv[8] = {v0.x*sc, v0.y*sc, v0.z*sc, v0.w*sc,
                       v1.x*sc, v1.y*sc, v1.z*sc, v1.w*sc};
        short8 hs, ls;
        #pragma unroll
        for (int q = 0; q < 8; ++q){
          __hip_bfloat16 h = __float2bfloat16(vv[q]);
          float hf = __bfloat162float(h);
          __hip_bfloat16 lo = __float2bfloat16(vv[q] - hf);
          hs[q] = reinterpret_cast<short&>(h);
          ls[q] = reinterpret_cast<short&>(lo);
        }
        const int kqph = kq ^ (srow & 3);
        *(short8*)&XhL[srow*32 + kqph*8] = hs;
        *(short8*)&XlL[srow*32 + kqph*8] = ls;
      }
      // ---- stage W (already bf16 hi/lo, [col][k]) ----
      const int kcw = t*32;
      #pragma unroll
      for (int kq2 = 0; kq2 < 2; ++kq2){
        const int kq = shalf*2 + kq2;
        short8 h = *(const short8*)&WTh[(size_t)srow*Kcat + kcw + kq*8];
        short8 l = *(const short8*)&WTl[(size_t)srow*Kcat + kcw + kq*8];
        const int kqph = kq ^ (srow & 3);
        *(short8*)&WhL[srow*32 + kqph*8] = h;
        *(short8*)&WlL[srow*32 + kqph*8] = l;
      }
    }
    __syncthreads();
    // ---- MFMA: wave (wr,wc) computes rows wr*64..+63 x cols wc*64..+63 ----
    short8 bh[4], bl[4];
    #pragma unroll
    for (int j = 0; j < 4; ++j){
      const int col = wc*64 + j*16 + l15;
      const int offb = col*32 + (lkq ^ (col & 3))*8;
      bh[j] = *(const short8*)&WhL[offb];
      bl[j] = *(const short8*)&WlL[offb];
    }
    #pragma unroll
    for (int m = 0; m < 4; ++m){
      const int row = wr*64 + m*16 + l15;
      const int offa = row*32 + (lkq ^ (row & 3))*8;
      short8 ah = *(const short8*)&XhL[offa];
      short8 al = *(const short8*)&XlL[offa];
      #pragma unroll
      for (int j = 0; j < 4; ++j){
        acc[m][j] = __builtin_amdgcn_mfma_f32_16x16x32_bf16(ah, bh[j], acc[m][j], 0, 0, 0);
        acc[m][j] = __builtin_amdgcn_mfma_f32_16x16x32_bf16(ah, bl[j], acc[m][j], 0, 0, 0);
        acc[m][j] = __builtin_amdgcn_mfma_f32_16x16x32_bf16(al, bh[j], acc[m][j], 0, 0, 0);
      }
    }
  }

  // ---- epilogue: relu + bias, store y, fused score partials ----
  #pragma unroll
  for (int m = 0; m < 4; ++m){
    float prt[4] = {0.f, 0.f, 0.f, 0.f};
    #pragma unroll
    for (int j = 0; j < 4; ++j){
      const int col = wc*64 + j*16 + l15;
      const float bcol = bias[col];
      const float pcol = p[col];
      f32x4 a = acc[m][j];
      #pragma unroll
      for (int r = 0; r < 4; ++r){
        const int row = wr*64 + m*16 + lkq*4 + r;
        float y = fmaxf(a[r] + bcol, 0.f);
        yout[(size_t)(row0 + row)*128 + col] = y;
        prt[r] = fmaf(y, pcol, prt[r]);
      }
    }
    #pragma unroll
    for (int r = 0; r < 4; ++r){
      #pragma unroll
      for (int msk = 8; msk >= 1; msk >>= 1) prt[r] += __shfl_xor(prt[r], msk);
      if (l15 == 0) sbuf[(wr*64 + m*16 + lkq*4 + r)*2 + wc] = prt[r];
    }
  }
  __syncthreads();
  if (tid < 128) score[row0 + tid] = sbuf[tid*2] + sbuf[tid*2 + 1];
}

// ---------------- per-graph top-k (slim): sort + alive/scale + rank-ordered selList ----------------

__global__ __launch_bounds__(1024) void topk_kernel(const float* __restrict__ score,
      const int* __restrict__ alive_cur, int* __restrict__ alive_next,
      float* __restrict__ scale, int* __restrict__ selList,
      const float* __restrict__ p, int m){
  __shared__ float lv[1024];
  __shared__ int   li[1024];
  __shared__ float rnorm;
  const int g = ((int)blockIdx.x & 7)*8 + ((int)blockIdx.x >> 3);   // graph g -> XCD g/8
  const int t = threadIdx.x;
  if (t < 64){
    float v0 = p[t], v1 = p[t + 64];
    float ss = v0*v0 + v1*v1;
    #pragma unroll
    for (int mm = 32; mm >= 1; mm >>= 1) ss += __shfl_xor(ss, mm);
    if (t == 0) rnorm = rsqrtf(ss);
  }
  const int node = g*NPER + t;
  bool ok = alive_cur ? (alive_cur[node] != 0) : true;
  float v = ok ? score[node] : -INFINITY;
  int idx = node;
  alive_next[node] = 0;
  scale[node] = 0.f;

  auto cex_shfl = [&](int stride, bool dirUp){
    float vj = __shfl_xor(v, stride);
    int   ij = __shfl_xor(idx, stride);
    bool iAmLow = (t & stride) == 0;
    bool mineFirst = (v > vj) || (v == vj && idx < ij);   // desc score, asc idx
    bool takeMine = ((dirUp == iAmLow) == mineFirst);
    v   = takeMine ? v   : vj;
    idx = takeMine ? idx : ij;
  };
  auto cex_lds = [&](int stride, bool dirUp){
    __syncthreads();
    lv[t] = v; li[t] = idx;
    __syncthreads();
    float vj = lv[t ^ stride];
    int   ij = li[t ^ stride];
    bool iAmLow = (t & stride) == 0;
    bool mineFirst = (v > vj) || (v == vj && idx < ij);
    bool takeMine = ((dirUp == iAmLow) == mineFirst);
    v   = takeMine ? v   : vj;
    idx = takeMine ? idx : ij;
  };

  #pragma unroll
  for (int size = 2; size <= 64; size <<= 1){
    const bool dirUp = (t & size) == 0;
    for (int stride = size >> 1; stride >= 1; stride >>= 1)
      cex_shfl(stride, dirUp);
  }
  #pragma unroll
  for (int size = 128; size <= 1024; size <<= 1){
    const bool dirUp = (t & size) == 0;
    for (int stride = size >> 1; stride >= 64; stride >>= 1)
      cex_lds(stride, dirUp);
    for (int stride = 32; stride >= 1; stride >>= 1)
      cex_shfl(stride, dirUp);
  }

  if (t < m){
    alive_next[idx] = 1;
    scale[idx] = tanhf(v * rnorm);
    selList[g*NPER + t] = idx;          // rank-ordered selected nodes
  }
}

// ---------------- readout (wide): per-graph max + mean of y*scale over SELECTED nodes ----------------

__global__ __launch_bounds__(1024) void readout_kernel(const float* __restrict__ y,
      const float* __restrict__ scale, const int* __restrict__ selList,
      float* __restrict__ h, int m, int firstLevel){
  __shared__ float smx[64][17];
  __shared__ float ssm[64][17];
  int g = ((int)blockIdx.x & 7)*8 + ((int)blockIdx.x >> 3);   // graph g -> XCD g/8
  int fq = blockIdx.y;       // 0..7
  int t = threadIdx.x;
  int c  = t >> 4;           // rank group 0..63
  int lf = t & 15;           // feature within group of 16
  int f  = fq*16 + lf;
  const int* sel = selList + g*NPER;
  float mx = -INFINITY, sm = 0.f;
  for (int r = c; r < m; r += 64){
    int node = sel[r];
    float o = y[(size_t)node*128 + f] * scale[node];
    mx = fmaxf(mx, o);
    sm += o;
  }
  smx[c][lf] = mx; ssm[c][lf] = sm;
  __syncthreads();
  for (int s = 32; s > 0; s >>= 1){
    if (c < s){
      smx[c][lf] = fmaxf(smx[c][lf], smx[c+s][lf]);
      ssm[c][lf] += ssm[c+s][lf];
    }
    __syncthreads();
  }
  if (c == 0){
    if (firstLevel){
      h[g*256 + f]       = smx[0][lf];
      h[g*256 + 128 + f] = ssm[0][lf] / (float)m;
    } else {
      h[g*256 + f]       += smx[0][lf];
      h[g*256 + 128 + f] += ssm[0][lf] / (float)m;
    }
  }
}

// ---------------- final MLP + log_softmax ----------------

__global__ __launch_bounds__(128) void final_kernel(const float* __restrict__ h,
      const float* __restrict__ l1w, const float* __restrict__ l1b,
      const float* __restrict__ l2w, const float* __restrict__ l2b,
      float* __restrict__ out){
  int g = blockIdx.x, t = threadIdx.x;
  __shared__ float hrow[256];
  __shared__ float red0[128], red1[128];
  hrow[t]       = h[g*256 + t];
  hrow[t + 128] = h[g*256 + 128 + t];
  __syncthreads();
  float a = l1b[t];
  for (int k = 0; k < 256; ++k) a = fmaf(hrow[k], l1w[k*128 + t], a);
  a = fmaxf(a, 0.f);
  red0[t] = a * l2w[t*2 + 0];
  red1[t] = a * l2w[t*2 + 1];
  __syncthreads();
  for (int s = 64; s > 0; s >>= 1){
    if (t < s){ red0[t] += red0[t + s]; red1[t] += red1[t + s]; }
    __syncthreads();
  }
  if (t == 0){
    float z0 = fmaxf(red0[0] + l2b[0], 0.f);
    float z1 = fmaxf(red1[0] + l2b[1], 0.f);
    float mz = fmaxf(z0, z1);
    float lse = mz + logf(expf(z0 - mz) + expf(z1 - mz));
    out[g*2 + 0] = z0 - lse;
    out[g*2 + 1] = z1 - lse;
  }
}

// ---------------- host ----------------

static inline size_t alignup(size_t x){ return (x + 255) & ~(size_t)255; }

extern "C" void kernel_launch(void* const* d_in, const int* in_sizes, int n_in,
                              void* d_out, int out_size, void* d_ws, size_t ws_size,
                              hipStream_t stream) {
  const float* x_in = (const float*)d_in[0];
  const int*   ei   = (const int*)d_in[1];
  const float* Wr[3] = {(const float*)d_in[3], (const float*)d_in[6], (const float*)d_in[9]};
  const float* Wn[3] = {(const float*)d_in[4], (const float*)d_in[7], (const float*)d_in[10]};
  const float* bs[3] = {(const float*)d_in[5], (const float*)d_in[8], (const float*)d_in[11]};
  const float* ps[3] = {(const float*)d_in[12], (const float*)d_in[13], (const float*)d_in[14]};
  const float* l1w = (const float*)d_in[15];
  const float* l1b = (const float*)d_in[16];
  const float* l2w = (const float*)d_in[17];
  const float* l2b = (const float*)d_in[18];
  float* out = (float*)d_out;

  char* w = (char*)d_ws;
  size_t o = 0;
  auto take = [&](size_t bytes) -> void* { void* p = w + o; o = alignup(o + bytes); return p; };
  int*   off    = (int*)  take((size_t)(NN + 1) * 4);
  int*   adj    = (int*)  take((size_t)NE * 4);
  int*   aliveA = (int*)  take((size_t)NN * 4);
  int*   aliveB = (int*)  take((size_t)NN * 4);
  float* scale  = (float*)take((size_t)NN * 4);
  float* score  = (float*)take((size_t)NN * 4);
  int*   selList= (int*)  take((size_t)NN * 4);
  float* h      = (float*)take((size_t)NB * 256 * 4);
  unsigned short* WTh = (unsigned short*)take((size_t)81920 * 2);
  unsigned short* WTl = (unsigned short*)take((size_t)81920 * 2);
  float* A      = (float*)take((size_t)NN * 128 * 4);  // y buffer (odd levels)
  float* Bb     = (float*)take((size_t)NN * 128 * 4);  // y buffer (even levels)
  (void)ws_size; (void)n_in; (void)in_sizes; (void)out_size;

  csr_kernel<<<NB, 1024, 0, stream>>>(ei, off, adj);
  wsplit_all_kernel<<<320, 256, 0, stream>>>(Wr[0], Wn[0], Wr[1], Wn[1], Wr[2], Wn[2], WTh, WTl);

  const int MS[3]   = {820, 656, 525};
  const int WOFF[3] = {0, 16384, 49152};
  const int KCAT[3] = {128, 256, 256};
  int* aliveCur = nullptr;
  int* aliveNext = aliveA;
  float* bufs[2] = {Bb, A};      // y_l lives in bufs[l&1]
  for (int l = 0; l < 3; ++l){
    const int Kx = (l == 0) ? 64 : 128;
    const int Ka = (l == 0) ? 64 : 128;
    float* aggb = bufs[l & 1];               // gather dst + conv yout (aliased by design)
    if (l == 0){
      gatherL_kernel<<<dim3(NB, 4), 1024, 0, stream>>>(x_in, 64, off, adj, nullptr, nullptr, aggb);
      conv_kernel<<<NN/128, 256, 0, stream>>>(x_in, 64, Kx/32, aggb, Ka/32, WTh + WOFF[0], WTl + WOFF[0], KCAT[0],
                                              bs[0], ps[0], nullptr, aggb, score);
    } else {
      const float* ysrc = bufs[(l - 1) & 1]; // previous level's y
      gatherL_kernel<<<dim3(NB, 8), 1024, 0, stream>>>(ysrc, 128, off, adj, scale, aliveCur, aggb);
      conv_kernel<<<NN/128, 256, 0, stream>>>(ysrc, 128, Kx/32, aggb, Ka/32, WTh + WOFF[l], WTl + WOFF[l], KCAT[l],
                                              bs[l], ps[l], scale, aggb, score);
    }
    topk_kernel<<<NB, 1024, 0, stream>>>(score, aliveCur, aliveNext, scale, selList, ps[l], MS[l]);
    readout_kernel<<<dim3(NB, 8), 1024, 0, stream>>>(aggb, scale, selList, h, MS[l], (l == 0) ? 1 : 0);
    aliveCur = aliveNext;
    aliveNext = (l == 0) ? aliveB : aliveA;
  }
  final_kernel<<<NB, 128, 0, stream>>>(h, l1w, l1b, l2w, l2b, out);
}

// Round 18
// 269.814 us; speedup vs baseline: 1.3204x; 1.3204x over previous
//
#include <hip/hip_runtime.h>
#include <hip/hip_bf16.h>
#include <math.h>

#define NN   65536      // total nodes
#define NPER 1024       // nodes per graph
#define NE   1048576    // edges
#define NB   64         // graphs
#define EPG  16384      // edges per graph (NE/NB, edges grouped by graph)

typedef __attribute__((ext_vector_type(8))) short short8;   // 8 bf16 = 4 VGPR
typedef __attribute__((ext_vector_type(4))) float f32x4;    // MFMA acc

// ---------------- CSR build: one block per graph (LDS bucket sort) ----------------

__global__ __launch_bounds__(1024) void csr_kernel(const int* __restrict__ ei,
      int* __restrict__ off, int* __restrict__ adj){
  __shared__ int hist[1024];
  __shared__ int wsum[16];
  const int g = ((int)blockIdx.x & 7)*8 + ((int)blockIdx.x >> 3);   // graph g -> XCD g/8
  const int t = threadIdx.x;
  const int ebase = g*EPG, nbase = g*NPER;
  hist[t] = 0;
  __syncthreads();
  int srcs[16], dls[16];
  #pragma unroll
  for (int i = 0; i < 16; ++i){
    int e = ebase + t + i*1024;
    srcs[i] = ei[e];
    dls[i]  = ei[NE + e] - nbase;
    atomicAdd(&hist[dls[i]], 1);
  }
  __syncthreads();
  int v = hist[t];
  int lane = t & 63, wid = t >> 6;
  int s = v;
  #pragma unroll
  for (int d = 1; d < 64; d <<= 1){
    int src = (lane >= d) ? (lane - d) : lane;
    int u = __shfl(s, src);
    if (lane >= d) s += u;
  }
  if (lane == 63) wsum[wid] = s;
  __syncthreads();
  if (wid == 0){
    int ws = (lane < 16) ? wsum[lane] : 0;
    #pragma unroll
    for (int d = 1; d < 16; d <<= 1){
      int src = (lane >= d) ? (lane - d) : lane;
      int u = __shfl(ws, src);
      if (lane >= d) ws += u;
    }
    if (lane < 16) wsum[lane] = ws;
  }
  __syncthreads();
  int base = (wid > 0) ? wsum[wid - 1] : 0;
  int excl = base + s - v;
  __syncthreads();
  hist[t] = excl;                        // becomes cursor
  off[nbase + t] = ebase + excl;
  if (g == NB - 1 && t == 1023) off[NN] = NE;
  __syncthreads();
  #pragma unroll
  for (int i = 0; i < 16; ++i){
    int pos = atomicAdd(&hist[dls[i]], 1);
    adj[ebase + pos] = srcs[i];
  }
}

// ---------------- aggregation: agg[w] = sum_e scl_e * y[src_e] ----------------

__global__ __launch_bounds__(1024) void gather_kernel(const float* __restrict__ x, int F,
      const int* __restrict__ off, const int* __restrict__ adjB, const float* __restrict__ scl,
      const int* __restrict__ deg2, float* __restrict__ agg, const int* __restrict__ alive){
  int bid = blockIdx.x;
  bid = (bid & 7) * (gridDim.x >> 3) + (bid >> 3);   // round-robin XCD -> contiguous chunks
  int w = bid*16 + ((int)threadIdx.x >> 6);
  int lane = threadIdx.x & 63;
  if (alive && !alive[w]) return;
  int s0 = off[w];
  int s1 = deg2 ? (s0 + deg2[w]) : off[w+1];
  if (F == 64){
    const char* xb = (const char*)x + (lane & 15)*16;
    int sub = lane >> 4;            // edge-group 0..3
    float4 a0 = make_float4(0.f,0.f,0.f,0.f), a1 = a0;
    if (s1 > s0){
      for (int e = s0; e < s1; e += 8){
        int e0 = e + sub, e1 = e + 4 + sub;
        bool ok0 = e0 < s1, ok1 = e1 < s1;
        size_t oA = (size_t)(unsigned)adjB[ok0 ? e0 : (s1 - 1)] << 8;
        size_t oB = (size_t)(unsigned)adjB[ok1 ? e1 : (s1 - 1)] << 8;
        float t0 = ok0 ? 1.f : 0.f, t1 = ok1 ? 1.f : 0.f;
        float4 vA = *(const float4*)(xb + oA);
        float4 vB = *(const float4*)(xb + oB);
        a0.x = fmaf(vA.x, t0, a0.x); a0.y = fmaf(vA.y, t0, a0.y);
        a0.z = fmaf(vA.z, t0, a0.z); a0.w = fmaf(vA.w, t0, a0.w);
        a1.x = fmaf(vB.x, t1, a1.x); a1.y = fmaf(vB.y, t1, a1.y);
        a1.z = fmaf(vB.z, t1, a1.z); a1.w = fmaf(vB.w, t1, a1.w);
      }
    }
    a0.x += a1.x; a0.y += a1.y; a0.z += a1.z; a0.w += a1.w;
    #pragma unroll
    for (int m = 16; m <= 32; m <<= 1){
      a0.x += __shfl_xor(a0.x, m);
      a0.y += __shfl_xor(a0.y, m);
      a0.z += __shfl_xor(a0.z, m);
      a0.w += __shfl_xor(a0.w, m);
    }
    if (lane < 16) *(float4*)&agg[(size_t)w*128 + (lane & 15)*4] = a0;
  } else {
    const char* xb = (const char*)x + (lane & 31)*16;
    int sub = lane >> 5;            // edge-group 0..1
    float4 a[4];
    #pragma unroll
    for (int i = 0; i < 4; ++i) a[i] = make_float4(0.f,0.f,0.f,0.f);
    if (s1 > s0){
      for (int e = s0; e < s1; e += 8){
        int ss[4]; float tv[4];
        #pragma unroll
        for (int i = 0; i < 4; ++i){
          int ei = e + 2*i + sub;
          bool okE = ei < s1;
          int ii = okE ? ei : (s1 - 1);
          ss[i] = adjB[ii];
          tv[i] = okE ? scl[ii] : 0.f;
        }
        #pragma unroll
        for (int i = 0; i < 4; ++i){
          float4 v = *(const float4*)(xb + (size_t)(unsigned)ss[i]);
          a[i].x = fmaf(v.x, tv[i], a[i].x);
          a[i].y = fmaf(v.y, tv[i], a[i].y);
          a[i].z = fmaf(v.z, tv[i], a[i].z);
          a[i].w = fmaf(v.w, tv[i], a[i].w);
        }
      }
    }
    float4 r;
    r.x = (a[0].x + a[1].x) + (a[2].x + a[3].x);
    r.y = (a[0].y + a[1].y) + (a[2].y + a[3].y);
    r.z = (a[0].z + a[1].z) + (a[2].z + a[3].z);
    r.w = (a[0].w + a[1].w) + (a[2].w + a[3].w);
    r.x += __shfl_xor(r.x, 32);
    r.y += __shfl_xor(r.y, 32);
    r.z += __shfl_xor(r.z, 32);
    r.w += __shfl_xor(r.w, 32);
    if (lane < 32) *(float4*)&agg[(size_t)w*128 + (lane & 31)*4] = r;
  }
}

// ---------------- W prep (all 3 levels, one launch) ----------------

__global__ __launch_bounds__(256) void wsplit_all_kernel(
      const float* __restrict__ Wr0, const float* __restrict__ Wn0,
      const float* __restrict__ Wr1, const float* __restrict__ Wn1,
      const float* __restrict__ Wr2, const float* __restrict__ Wn2,
      unsigned short* __restrict__ WTh, unsigned short* __restrict__ WTl){
  int idx = blockIdx.x*256 + threadIdx.x;       // 0..81919
  int rel, Kcat, Kx, base;
  const float *Wr, *Wn;
  if (idx < 16384){ rel = idx;          Kcat = 128; Kx = 64;  base = 0;     Wr = Wr0; Wn = Wn0; }
  else if (idx < 49152){ rel = idx - 16384; Kcat = 256; Kx = 128; base = 16384; Wr = Wr1; Wn = Wn1; }
  else { rel = idx - 49152; Kcat = 256; Kx = 128; base = 49152; Wr = Wr2; Wn = Wn2; }
  int c = rel & 127, k = rel >> 7;
  float w = (k < Kx) ? Wr[k*128 + c] : Wn[(k - Kx)*128 + c];
  __hip_bfloat16 h = __float2bfloat16(w);
  float hf = __bfloat162float(h);
  __hip_bfloat16 l = __float2bfloat16(w - hf);
  WTh[base + c*Kcat + k] = reinterpret_cast<unsigned short&>(h);
  WTl[base + c*Kcat + k] = reinterpret_cast<unsigned short&>(l);
}

// ---------------- conv via bf16x3 MFMA: y = relu((scale.x)@Wr + agg@Wn + b), score = y.p ----

__global__ __launch_bounds__(256, 2) void conv_kernel(const float* __restrict__ xsrc, int strideX, int ntx,
      const float* aggb, int nta,
      const unsigned short* __restrict__ WTh, const unsigned short* __restrict__ WTl, int Kcat,
      const float* __restrict__ bias, const float* __restrict__ p, const float* __restrict__ scaleX,
      float* yout, float* __restrict__ score){
  __shared__ unsigned short XhL[128*32], XlL[128*32];
  __shared__ unsigned short WhL[128*32], WlL[128*32];
  __shared__ float sbuf[128*2];
  const int tid = threadIdx.x;
  const int rblk = ((int)blockIdx.x & 7) * ((int)gridDim.x >> 3) + ((int)blockIdx.x >> 3);
  const int row0 = rblk * 128;
  const int srow = tid & 127;          // staging row (X) / col (W)
  const int shalf = tid >> 7;          // staging k-half (16 k each)
  const int lane = tid & 63;
  const int wid = tid >> 6;            // 4 waves: 2x2
  const int wr = wid >> 1, wc = wid & 1;
  const int l15 = lane & 15, lkq = lane >> 4;

  const float xscale = scaleX ? scaleX[row0 + srow] : 1.f;

  f32x4 acc[4][4];
  #pragma unroll
  for (int m = 0; m < 4; ++m)
    #pragma unroll
    for (int j = 0; j < 4; ++j)
      acc[m][j] = (f32x4){0.f, 0.f, 0.f, 0.f};

  const int nt = ntx + nta;
  for (int t = 0; t < nt; ++t){
    __syncthreads();                   // previous tile's compute done
    // ---- stage X (fp32 -> scale -> bf16 hi/lo) ----
    {
      const float* Xs   = (t < ntx) ? xsrc : aggb;
      const int stride  = (t < ntx) ? strideX : 128;
      const int kc      = (t < ntx) ? t*32 : (t - ntx)*32;
      const float sc    = (t < ntx) ? xscale : 1.f;
      #pragma unroll
      for (int kq2 = 0; kq2 < 2; ++kq2){
        const int kq = shalf*2 + kq2;
        const float* xp = Xs + (size_t)(row0 + srow)*stride + kc + kq*8;
        float4 v0 = *(const float4*)(xp);
        float4 v1 = *(const float4*)(xp + 4);
        float vv[8] = {v0.x*sc, v0.y*sc, v0.z*sc, v0.w*sc,
                       v1.x*sc, v1.y*sc, v1.z*sc, v1.w*sc};
        short8 hs, ls;
        #pragma unroll
        for (int q = 0; q < 8; ++q){
          __hip_bfloat16 h = __float2bfloat16(vv[q]);
          float hf = __bfloat162float(h);
          __hip_bfloat16 lo = __float2bfloat16(vv[q] - hf);
          hs[q] = reinterpret_cast<short&>(h);
          ls[q] = reinterpret_cast<short&>(lo);
        }
        const int kqph = kq ^ (srow & 3);
        *(short8*)&XhL[srow*32 + kqph*8] = hs;
        *(short8*)&XlL[srow*32 + kqph*8] = ls;
      }
      // ---- stage W (already bf16 hi/lo, [col][k]) ----
      const int kcw = t*32;
      #pragma unroll
      for (int kq2 = 0; kq2 < 2; ++kq2){
        const int kq = shalf*2 + kq2;
        short8 h = *(const short8*)&WTh[(size_t)srow*Kcat + kcw + kq*8];
        short8 l = *(const short8*)&WTl[(size_t)srow*Kcat + kcw + kq*8];
        const int kqph = kq ^ (srow & 3);
        *(short8*)&WhL[srow*32 + kqph*8] = h;
        *(short8*)&WlL[srow*32 + kqph*8] = l;
      }
    }
    __syncthreads();
    // ---- MFMA: wave (wr,wc) computes rows wr*64..+63 x cols wc*64..+63 ----
    short8 bh[4], bl[4];
    #pragma unroll
    for (int j = 0; j < 4; ++j){
      const int col = wc*64 + j*16 + l15;
      const int offb = col*32 + (lkq ^ (col & 3))*8;
      bh[j] = *(const short8*)&WhL[offb];
      bl[j] = *(const short8*)&WlL[offb];
    }
    #pragma unroll
    for (int m = 0; m < 4; ++m){
      const int row = wr*64 + m*16 + l15;
      const int offa = row*32 + (lkq ^ (row & 3))*8;
      short8 ah = *(const short8*)&XhL[offa];
      short8 al = *(const short8*)&XlL[offa];
      #pragma unroll
      for (int j = 0; j < 4; ++j){
        acc[m][j] = __builtin_amdgcn_mfma_f32_16x16x32_bf16(ah, bh[j], acc[m][j], 0, 0, 0);
        acc[m][j] = __builtin_amdgcn_mfma_f32_16x16x32_bf16(ah, bl[j], acc[m][j], 0, 0, 0);
        acc[m][j] = __builtin_amdgcn_mfma_f32_16x16x32_bf16(al, bh[j], acc[m][j], 0, 0, 0);
      }
    }
  }

  // ---- epilogue: relu + bias, store y, fused score partials ----
  #pragma unroll
  for (int m = 0; m < 4; ++m){
    float prt[4] = {0.f, 0.f, 0.f, 0.f};
    #pragma unroll
    for (int j = 0; j < 4; ++j){
      const int col = wc*64 + j*16 + l15;
      const float bcol = bias[col];
      const float pcol = p[col];
      f32x4 a = acc[m][j];
      #pragma unroll
      for (int r = 0; r < 4; ++r){
        const int row = wr*64 + m*16 + lkq*4 + r;
        float y = fmaxf(a[r] + bcol, 0.f);
        yout[(size_t)(row0 + row)*128 + col] = y;
        prt[r] = fmaf(y, pcol, prt[r]);
      }
    }
    #pragma unroll
    for (int r = 0; r < 4; ++r){
      #pragma unroll
      for (int msk = 8; msk >= 1; msk >>= 1) prt[r] += __shfl_xor(prt[r], msk);
      if (l15 == 0) sbuf[(wr*64 + m*16 + lkq*4 + r)*2 + wc] = prt[r];
    }
  }
  __syncthreads();
  if (tid < 128) score[row0 + tid] = sbuf[tid*2] + sbuf[tid*2 + 1];
}

// ---------------- per-graph top-k (slim): sort + alive/scale + rank-ordered selList ----------------

__global__ __launch_bounds__(1024) void topk_kernel(const float* __restrict__ score,
      const int* __restrict__ alive_cur, int* __restrict__ alive_next,
      float* __restrict__ scale, int* __restrict__ selList,
      const float* __restrict__ p, int m){
  __shared__ float lv[1024];
  __shared__ int   li[1024];
  __shared__ float rnorm;
  const int g = ((int)blockIdx.x & 7)*8 + ((int)blockIdx.x >> 3);   // graph g -> XCD g/8
  const int t = threadIdx.x;
  if (t < 64){
    float v0 = p[t], v1 = p[t + 64];
    float ss = v0*v0 + v1*v1;
    #pragma unroll
    for (int mm = 32; mm >= 1; mm >>= 1) ss += __shfl_xor(ss, mm);
    if (t == 0) rnorm = rsqrtf(ss);
  }
  const int node = g*NPER + t;
  bool ok = alive_cur ? (alive_cur[node] != 0) : true;
  float v = ok ? score[node] : -INFINITY;
  int idx = node;
  alive_next[node] = 0;
  scale[node] = 0.f;

  auto cex_shfl = [&](int stride, bool dirUp){
    float vj = __shfl_xor(v, stride);
    int   ij = __shfl_xor(idx, stride);
    bool iAmLow = (t & stride) == 0;
    bool mineFirst = (v > vj) || (v == vj && idx < ij);   // desc score, asc idx
    bool takeMine = ((dirUp == iAmLow) == mineFirst);
    v   = takeMine ? v   : vj;
    idx = takeMine ? idx : ij;
  };
  auto cex_lds = [&](int stride, bool dirUp){
    __syncthreads();
    lv[t] = v; li[t] = idx;
    __syncthreads();
    float vj = lv[t ^ stride];
    int   ij = li[t ^ stride];
    bool iAmLow = (t & stride) == 0;
    bool mineFirst = (v > vj) || (v == vj && idx < ij);
    bool takeMine = ((dirUp == iAmLow) == mineFirst);
    v   = takeMine ? v   : vj;
    idx = takeMine ? idx : ij;
  };

  #pragma unroll
  for (int size = 2; size <= 64; size <<= 1){
    const bool dirUp = (t & size) == 0;
    for (int stride = size >> 1; stride >= 1; stride >>= 1)
      cex_shfl(stride, dirUp);
  }
  #pragma unroll
  for (int size = 128; size <= 1024; size <<= 1){
    const bool dirUp = (t & size) == 0;
    for (int stride = size >> 1; stride >= 64; stride >>= 1)
      cex_lds(stride, dirUp);
    for (int stride = 32; stride >= 1; stride >>= 1)
      cex_shfl(stride, dirUp);
  }

  if (t < m){
    alive_next[idx] = 1;
    scale[idx] = tanhf(v * rnorm);
    selList[g*NPER + t] = idx;          // rank-ordered selected nodes
  }
}

// ---------------- readout (wide): per-graph max + mean of y*scale over SELECTED nodes ----------------

__global__ __launch_bounds__(1024) void readout_kernel(const float* __restrict__ y,
      const float* __restrict__ scale, const int* __restrict__ selList,
      float* __restrict__ h, int m, int firstLevel){
  __shared__ float smx[64][17];
  __shared__ float ssm[64][17];
  int g = ((int)blockIdx.x & 7)*8 + ((int)blockIdx.x >> 3);   // graph g -> XCD g/8
  int fq = blockIdx.y;       // 0..7
  int t = threadIdx.x;
  int c  = t >> 4;           // rank group 0..63
  int lf = t & 15;           // feature within group of 16
  int f  = fq*16 + lf;
  const int* sel = selList + g*NPER;
  float mx = -INFINITY, sm = 0.f;
  for (int r = c; r < m; r += 64){
    int node = sel[r];
    float o = y[(size_t)node*128 + f] * scale[node];
    mx = fmaxf(mx, o);
    sm += o;
  }
  smx[c][lf] = mx; ssm[c][lf] = sm;
  __syncthreads();
  for (int s = 32; s > 0; s >>= 1){
    if (c < s){
      smx[c][lf] = fmaxf(smx[c][lf], smx[c+s][lf]);
      ssm[c][lf] += ssm[c+s][lf];
    }
    __syncthreads();
  }
  if (c == 0){
    if (firstLevel){
      h[g*256 + f]       = smx[0][lf];
      h[g*256 + 128 + f] = ssm[0][lf] / (float)m;
    } else {
      h[g*256 + f]       += smx[0][lf];
      h[g*256 + 128 + f] += ssm[0][lf] / (float)m;
    }
  }
}

// ---------------- per-level edge compaction (wide: 4096 blocks, 16 nodes each) ----------------

__global__ __launch_bounds__(1024) void compact_kernel(const int* __restrict__ off, const int* __restrict__ adj,
      const float* __restrict__ scale, const int* __restrict__ alive,
      int* __restrict__ adj2, float* __restrict__ scl2, int* __restrict__ deg2){
  int w = blockIdx.x*16 + ((int)threadIdx.x >> 6);
  int lane = threadIdx.x & 63;
  if (!alive[w]){ if (lane == 0) deg2[w] = 0; return; }
  int s0 = off[w], s1 = off[w+1];
  int base = s0;
  for (int e0 = s0; e0 < s1; e0 += 64){
    int e = e0 + lane;
    bool okE = e < s1;
    int s = adj[okE ? e : (s1 - 1)];
    float t = scale[s];
    bool keep = okE && (t != 0.f);
    unsigned long long m = __ballot(keep);
    int pos = base + __popcll(m & ((1ull << lane) - 1ull));
    if (keep){ adj2[pos] = s << 9; scl2[pos] = t; }
    base += __popcll(m);
  }
  if (lane == 0) deg2[w] = base - s0;
}

// ---------------- final MLP + log_softmax ----------------

__global__ __launch_bounds__(128) void final_kernel(const float* __restrict__ h,
      const float* __restrict__ l1w, const float* __restrict__ l1b,
      const float* __restrict__ l2w, const float* __restrict__ l2b,
      float* __restrict__ out){
  int g = blockIdx.x, t = threadIdx.x;
  __shared__ float hrow[256];
  __shared__ float red0[128], red1[128];
  hrow[t]       = h[g*256 + t];
  hrow[t + 128] = h[g*256 + 128 + t];
  __syncthreads();
  float a = l1b[t];
  for (int k = 0; k < 256; ++k) a = fmaf(hrow[k], l1w[k*128 + t], a);
  a = fmaxf(a, 0.f);
  red0[t] = a * l2w[t*2 + 0];
  red1[t] = a * l2w[t*2 + 1];
  __syncthreads();
  for (int s = 64; s > 0; s >>= 1){
    if (t < s){ red0[t] += red0[t + s]; red1[t] += red1[t + s]; }
    __syncthreads();
  }
  if (t == 0){
    float z0 = fmaxf(red0[0] + l2b[0], 0.f);
    float z1 = fmaxf(red1[0] + l2b[1], 0.f);
    float mz = fmaxf(z0, z1);
    float lse = mz + logf(expf(z0 - mz) + expf(z1 - mz));
    out[g*2 + 0] = z0 - lse;
    out[g*2 + 1] = z1 - lse;
  }
}

// ---------------- host ----------------

static inline size_t alignup(size_t x){ return (x + 255) & ~(size_t)255; }

extern "C" void kernel_launch(void* const* d_in, const int* in_sizes, int n_in,
                              void* d_out, int out_size, void* d_ws, size_t ws_size,
                              hipStream_t stream) {
  const float* x_in = (const float*)d_in[0];
  const int*   ei   = (const int*)d_in[1];
  const float* Wr[3] = {(const float*)d_in[3], (const float*)d_in[6], (const float*)d_in[9]};
  const float* Wn[3] = {(const float*)d_in[4], (const float*)d_in[7], (const float*)d_in[10]};
  const float* bs[3] = {(const float*)d_in[5], (const float*)d_in[8], (const float*)d_in[11]};
  const float* ps[3] = {(const float*)d_in[12], (const float*)d_in[13], (const float*)d_in[14]};
  const float* l1w = (const float*)d_in[15];
  const float* l1b = (const float*)d_in[16];
  const float* l2w = (const float*)d_in[17];
  const float* l2b = (const float*)d_in[18];
  float* out = (float*)d_out;

  char* w = (char*)d_ws;
  size_t o = 0;
  auto take = [&](size_t bytes) -> void* { void* p = w + o; o = alignup(o + bytes); return p; };
  int*   off    = (int*)  take((size_t)(NN + 1) * 4);
  int*   adj    = (int*)  take((size_t)NE * 4);
  int*   adj2   = (int*)  take((size_t)NE * 4);
  float* scl2   = (float*)take((size_t)NE * 4);
  int*   deg2   = (int*)  take((size_t)NN * 4);
  int*   aliveA = (int*)  take((size_t)NN * 4);
  int*   aliveB = (int*)  take((size_t)NN * 4);
  float* scale  = (float*)take((size_t)NN * 4);
  float* score  = (float*)take((size_t)NN * 4);
  int*   selList= (int*)  take((size_t)NN * 4);
  float* h      = (float*)take((size_t)NB * 256 * 4);
  unsigned short* WTh = (unsigned short*)take((size_t)81920 * 2);
  unsigned short* WTl = (unsigned short*)take((size_t)81920 * 2);
  float* A      = (float*)take((size_t)NN * 128 * 4);  // y buffer (odd levels)
  float* Bb     = (float*)take((size_t)NN * 128 * 4);  // y buffer (even levels)
  (void)ws_size; (void)n_in; (void)in_sizes; (void)out_size;

  csr_kernel<<<NB, 1024, 0, stream>>>(ei, off, adj);
  wsplit_all_kernel<<<320, 256, 0, stream>>>(Wr[0], Wn[0], Wr[1], Wn[1], Wr[2], Wn[2], WTh, WTl);

  const int MS[3]   = {820, 656, 525};
  const int WOFF[3] = {0, 16384, 49152};
  const int KCAT[3] = {128, 256, 256};
  int* aliveCur = nullptr;
  int* aliveNext = aliveA;
  float* bufs[2] = {Bb, A};      // y_l lives in bufs[l&1]
  for (int l = 0; l < 3; ++l){
    const int Kx = (l == 0) ? 64 : 128;
    const int Ka = (l == 0) ? 64 : 128;
    float* aggb = bufs[l & 1];               // gather dst + conv yout (aliased by design)
    if (l == 0){
      gather_kernel<<<NN/16, 1024, 0, stream>>>(x_in, 64, off, adj, nullptr, nullptr, aggb, nullptr);
      conv_kernel<<<NN/128, 256, 0, stream>>>(x_in, 64, Kx/32, aggb, Ka/32, WTh + WOFF[0], WTl + WOFF[0], KCAT[0],
                                              bs[0], ps[0], nullptr, aggb, score);
    } else {
      const float* ysrc = bufs[(l - 1) & 1]; // previous level's y
      gather_kernel<<<NN/16, 1024, 0, stream>>>(ysrc, 128, off, adj2, scl2, deg2, aggb, aliveCur);
      conv_kernel<<<NN/128, 256, 0, stream>>>(ysrc, 128, Kx/32, aggb, Ka/32, WTh + WOFF[l], WTl + WOFF[l], KCAT[l],
                                              bs[l], ps[l], scale, aggb, score);
    }
    topk_kernel<<<NB, 1024, 0, stream>>>(score, aliveCur, aliveNext, scale, selList, ps[l], MS[l]);
    readout_kernel<<<dim3(NB, 8), 1024, 0, stream>>>(aggb, scale, selList, h, MS[l], (l == 0) ? 1 : 0);
    if (l < 2)
      compact_kernel<<<NN/16, 1024, 0, stream>>>(off, adj, scale, aliveNext, adj2, scl2, deg2);
    aliveCur = aliveNext;
    aliveNext = (l == 0) ? aliveB : aliveA;
  }
  final_kernel<<<NB, 128, 0, stream>>>(h, l1w, l1b, l2w, l2b, out);
}